// Round 5
// baseline (271.112 us; speedup 1.0000x reference)
//
#include <hip/hip_runtime.h>
#include <hip/hip_cooperative_groups.h>
#include <math.h>

namespace cg = cooperative_groups;

constexpr int N_ITEMS = 512;
constexpr int TS      = 2048;    // TABLE_SAMPLES
constexpr int FULL    = 32768;
constexpr int PADDED  = 65536;
constexpr int NPAIR   = 512;     // BATCH * N_EVENTS
constexpr int NBLK    = NPAIR * 2;   // 1024 blocks: (pair, half)

using f4 = __attribute__((ext_vector_type(4))) float;

// ---- order-preserving float <-> uint encoding for min/max ----
__device__ __forceinline__ unsigned fenc(float f) {
    unsigned u = __float_as_uint(f);
    return (u & 0x80000000u) ? ~u : (u | 0x80000000u);
}
__device__ __forceinline__ float fdec(unsigned e) {
    return __uint_as_float((e & 0x80000000u) ? (e & 0x7FFFFFFFu) : ~e);
}

// ws layout (bytes):
//   [0     .. 4095]  min partials, unsigned[1024]   (every slot rewritten each call)
//   [4096  .. 8191]  max partials, unsigned[1024]
//   [8192  .. 10239] idx, int[512]
//   [10240 .. 12287] w,   float[512]

__global__ void __launch_bounds__(256, 4) k_fused(const float* __restrict__ items,
                                                  const float* __restrict__ sel,
                                                  const float* __restrict__ noise,
                                                  unsigned* __restrict__ ws_min,
                                                  unsigned* __restrict__ ws_max,
                                                  int* __restrict__ ws_idx,
                                                  float* __restrict__ ws_w,
                                                  float* __restrict__ out) {
    __shared__ float row[TS];
    __shared__ unsigned sred[8];
    __shared__ float sb[2];
    __shared__ int sidx;

    int b = blockIdx.x, t = threadIdx.x;
    int p = b >> 1, q = b & 1;
    int wave = t >> 6, lane = t & 63;

    // ======== Phase A ========
    // A1: min/max partial over a 4 KB slice of the items table (1 f4/thread)
    {
        const f4* items4 = (const f4*)items;
        f4 v = items4[b * 256 + t];                  // 1024*256 f4 = whole table
        unsigned e0 = fenc(v.x), e1 = fenc(v.y), e2 = fenc(v.z), e3 = fenc(v.w);
        unsigned lmin = min(min(e0, e1), min(e2, e3));
        unsigned lmax = max(max(e0, e1), max(e2, e3));
        for (int off = 32; off > 0; off >>= 1) {
            lmin = min(lmin, (unsigned)__shfl_xor((int)lmin, off));
            lmax = max(lmax, (unsigned)__shfl_xor((int)lmax, off));
        }
        if (lane == 0) { sred[wave] = lmin; sred[4 + wave] = lmax; }
        __syncthreads();
        if (t == 0) {
            ws_min[b] = min(min(sred[0], sred[1]), min(sred[2], sred[3]));
            ws_max[b] = max(max(sred[4], sred[5]), max(sred[6], sred[7]));
        }
    }

    // A2: sparse-softmax selection — blocks 0..511, wave 0 only (pair = b)
    if (b < NPAIR && wave == 0) {
        const float* s = sel + (size_t)b * N_ITEMS;
        float x[8];
        float vmax = -INFINITY;
        int   imax = 0x7FFFFFFF;
        #pragma unroll
        for (int k = 0; k < 8; ++k) {
            int i = lane + k * 64;
            x[k] = s[i];
            if (x[k] > vmax) { vmax = x[k]; imax = i; }  // ascending -> first occurrence
        }
        for (int off = 32; off > 0; off >>= 1) {
            float ov = __shfl_xor(vmax, off);
            int   oi = __shfl_xor(imax, off);
            if (ov > vmax || (ov == vmax && oi < imax)) { vmax = ov; imax = oi; }
        }
        float se = 0.0f;
        #pragma unroll
        for (int k = 0; k < 8; ++k) se += expf(x[k] - vmax);
        for (int off = 32; off > 0; off >>= 1) se += __shfl_xor(se, off);
        if (lane == 0) { ws_idx[b] = imax; ws_w[b] = 1.0f / se; }
    }

    // A3: zero this block's 64 KB pad chunk (regular stores)
    {
        f4* pad4 = (f4*)(out + (size_t)p * PADDED + FULL + (size_t)q * ((PADDED - FULL) / 2));
        f4 z = {0.f, 0.f, 0.f, 0.f};
        #pragma unroll
        for (int k = 0; k < 16; ++k)
            pad4[t + k * 256] = z;
    }

    __threadfence();
    cg::this_grid().sync();

    // ======== Phase B ========
    // B1: reduce the 1024 min/max partials; fetch this pair's idx/w
    {
        const uint4* m4 = (const uint4*)ws_min;
        const uint4* x4 = (const uint4*)ws_max;
        uint4 a = m4[t];
        uint4 c = x4[t];
        unsigned gmin = min(min(a.x, a.y), min(a.z, a.w));
        unsigned gmax = max(max(c.x, c.y), max(c.z, c.w));
        for (int off = 32; off > 0; off >>= 1) {
            gmin = min(gmin, (unsigned)__shfl_xor((int)gmin, off));
            gmax = max(gmax, (unsigned)__shfl_xor((int)gmax, off));
        }
        if (lane == 0) { sred[wave] = gmin; sred[4 + wave] = gmax; }
        __syncthreads();
        if (t == 0) {
            unsigned m0 = min(min(sred[0], sred[1]), min(sred[2], sred[3]));
            unsigned m1 = max(max(sred[4], sred[5]), max(sred[6], sred[7]));
            float minv  = fdec(m0);
            float maxv  = fdec(m1);
            float denom = (maxv - minv) + 0.001f;
            float scale = ws_w[p] / denom;
            sb[0] = scale;
            sb[1] = -minv * scale;
            sidx  = ws_idx[p];
        }
        __syncthreads();
    }
    float scale = sb[0], bias = sb[1];
    int   idx   = sidx;

    // B2: stage the normalized*w row in LDS
    {
        const f4* it4 = (const f4*)(items + (size_t)idx * TS);
        f4 r0 = it4[t];
        f4 r1 = it4[t + 256];
        row[t * 4 + 0] = fmaf(r0.x, scale, bias);
        row[t * 4 + 1] = fmaf(r0.y, scale, bias);
        row[t * 4 + 2] = fmaf(r0.z, scale, bias);
        row[t * 4 + 3] = fmaf(r0.w, scale, bias);
        row[(t + 256) * 4 + 0] = fmaf(r1.x, scale, bias);
        row[(t + 256) * 4 + 1] = fmaf(r1.y, scale, bias);
        row[(t + 256) * 4 + 2] = fmaf(r1.z, scale, bias);
        row[(t + 256) * 4 + 3] = fmaf(r1.w, scale, bias);
    }
    __syncthreads();

    // B3: stream noise -> interp -> amp, 2x unrolled (16 f4/thread total)
    constexpr int CHUNK = FULL / 2;   // 16384 floats per (pair, half)
    const f4* nz4 = (const f4*)(noise + (size_t)p * FULL + (size_t)q * CHUNK);
    f4*       o4  = (f4*)(out + (size_t)p * PADDED + (size_t)q * CHUNK);
    int tbase = q * CHUNK;

    for (int v = t; v < CHUNK / 4; v += 512) {       // 8 iters, 2 f4 each
        int v2 = v + 256;
        f4 na = nz4[v];
        f4 nb = nz4[v2];
        f4 oa, ob;
        #pragma unroll
        for (int half = 0; half < 2; ++half) {
            int   tv = tbase + (half ? v2 : v) * 4;
            f4    nz = half ? nb : na;
            float pos0 = ((float)tv + 0.5f) * 0.0625f - 0.5f;
            f4 o;
            #pragma unroll
            for (int j = 0; j < 4; ++j) {
                float pj = fminf(fmaxf(pos0 + (float)j * 0.0625f, 0.0f), (float)(TS - 1));
                int   lj = (int)pj;                  // trunc == floor (>=0)
                int   hj = min(lj + 1, TS - 1);
                float fr = pj - (float)lj;
                float amp = row[lj] * (1.0f - fr) + row[hj] * fr;
                o[j] = amp * nz[j];
            }
            if (half) ob = o; else oa = o;
        }
        o4[v]  = oa;
        o4[v2] = ob;
    }
}

extern "C" void kernel_launch(void* const* d_in, const int* in_sizes, int n_in,
                              void* d_out, int out_size, void* d_ws, size_t ws_size,
                              hipStream_t stream) {
    const float* sel   = (const float*)d_in[0];   // [8,64,512]
    const float* items = (const float*)d_in[1];   // [512,2048]
    const float* noise = (const float*)d_in[2];   // [8,64,32768]
    float* out = (float*)d_out;                   // [8,64,65536]

    unsigned* ws_min = (unsigned*)d_ws;
    unsigned* ws_max = (unsigned*)((char*)d_ws + 4096);
    int*      ws_idx = (int*)((char*)d_ws + 8192);
    float*    ws_w   = (float*)((char*)d_ws + 10240);

    void* args[] = { (void*)&items, (void*)&sel, (void*)&noise,
                     (void*)&ws_min, (void*)&ws_max, (void*)&ws_idx, (void*)&ws_w,
                     (void*)&out };
    hipLaunchCooperativeKernel((const void*)k_fused, dim3(NBLK), dim3(256),
                               args, 0, stream);
}

// Round 6
// 39.167 us; speedup vs baseline: 6.9220x; 6.9220x over previous
//
#include <hip/hip_runtime.h>
#include <math.h>

constexpr int N_ITEMS = 512;
constexpr int TS      = 2048;    // TABLE_SAMPLES
constexpr int FULL    = 32768;
constexpr int PADDED  = 65536;
constexpr int NPAIR   = 512;     // BATCH * N_EVENTS
constexpr int SPLIT   = 4;       // main: blocks per pair

using f4 = __attribute__((ext_vector_type(4))) float;

// ---- order-preserving float <-> uint encoding for min/max over partials ----
__device__ __forceinline__ unsigned fenc(float f) {
    unsigned u = __float_as_uint(f);
    return (u & 0x80000000u) ? ~u : (u | 0x80000000u);
}
__device__ __forceinline__ float fdec(unsigned e) {
    return __uint_as_float((e & 0x80000000u) ? (e & 0x7FFFFFFFu) : ~e);
}

// ws layout (bytes):
//   [0    .. 1023]  min partials, unsigned[256]
//   [1024 .. 2047]  max partials, unsigned[256]
//   [2048 .. 4095]  idx, int[512]
//   [4096 .. 6143]  w,   float[512]

// k_prep, grid = 1024 x 256  (identical to the 40.9us R3 version):
//   every block    : nt-store 64 KB of the zero pad (its pair-half)
//   blocks 0..255  : min/max partials over 1/256 of the items table
//   blocks 256..383: sparse-softmax selection, 4 pairs per block (1 wave each)
__global__ void __launch_bounds__(256) k_prep(const f4* __restrict__ items4,
                                              const float* __restrict__ sel,
                                              unsigned* __restrict__ ws_min,
                                              unsigned* __restrict__ ws_max,
                                              int* __restrict__ ws_idx,
                                              float* __restrict__ ws_w,
                                              float* __restrict__ out) {
    __shared__ unsigned smin[4], smax[4];
    int blk = blockIdx.x;
    int tid = threadIdx.x;

    if (blk < 256) {
        unsigned lmin = 0xFFFFFFFFu, lmax = 0u;
        const int NV = (N_ITEMS * TS) / 4;          // 262144 float4
        for (int i = blk * 256 + tid; i < NV; i += 256 * 256) {   // 4 iters
            f4 v = items4[i];
            unsigned e0 = fenc(v.x), e1 = fenc(v.y), e2 = fenc(v.z), e3 = fenc(v.w);
            lmin = min(min(min(lmin, e0), min(e1, e2)), e3);
            lmax = max(max(max(lmax, e0), max(e1, e2)), e3);
        }
        for (int off = 32; off > 0; off >>= 1) {
            lmin = min(lmin, (unsigned)__shfl_xor((int)lmin, off));
            lmax = max(lmax, (unsigned)__shfl_xor((int)lmax, off));
        }
        int wave = tid >> 6;
        if ((tid & 63) == 0) { smin[wave] = lmin; smax[wave] = lmax; }
        __syncthreads();
        if (tid == 0) {
            ws_min[blk] = min(min(smin[0], smin[1]), min(smin[2], smin[3]));
            ws_max[blk] = max(max(smax[0], smax[1]), max(smax[2], smax[3]));
        }
    } else if (blk < 384) {
        int p    = (blk - 256) * 4 + (tid >> 6);
        int lane = tid & 63;
        const float* s = sel + (size_t)p * N_ITEMS;
        float x[8];
        float vmax = -INFINITY;
        int   imax = 0x7FFFFFFF;
        #pragma unroll
        for (int k = 0; k < 8; ++k) {
            int i = lane + k * 64;
            x[k] = s[i];
            if (x[k] > vmax) { vmax = x[k]; imax = i; }  // ascending -> first occurrence
        }
        for (int off = 32; off > 0; off >>= 1) {
            float ov = __shfl_xor(vmax, off);
            int   oi = __shfl_xor(imax, off);
            if (ov > vmax || (ov == vmax && oi < imax)) { vmax = ov; imax = oi; }
        }
        float se = 0.0f;
        #pragma unroll
        for (int k = 0; k < 8; ++k) se += expf(x[k] - vmax);
        for (int off = 32; off > 0; off >>= 1) se += __shfl_xor(se, off);
        if (lane == 0) { ws_idx[p] = imax; ws_w[p] = 1.0f / se; }
    }

    // every block: zero its pair-half of the pad region (nt stores)
    {
        int p = blk >> 1, h = blk & 1;
        f4* pad4 = (f4*)(out + (size_t)p * PADDED + FULL + (size_t)h * (PADDED - FULL) / 2);
        f4 z = {0.f, 0.f, 0.f, 0.f};
        #pragma unroll
        for (int v = 0; v < 16; ++v)                 // 16 * 256 * 16B = 64 KB
            __builtin_nontemporal_store(z, &pad4[tid + v * 256]);
    }
}

// k_main, grid = 2048 x 256: block = (pair, quarter). 8 blocks/CU, 8 waves/SIMD.
// Prologue: per-wave (barrier-free) reduce of the 256 min/max partials; one
// barrier for LDS row staging. Body: prefetch all 8 noise f4 into registers,
// then interp + nt-store.
__global__ void __launch_bounds__(256, 8) k_main(const float* __restrict__ items,
                                                 const float* __restrict__ noise,
                                                 const unsigned* __restrict__ ws_min,
                                                 const unsigned* __restrict__ ws_max,
                                                 const int* __restrict__ ws_idx,
                                                 const float* __restrict__ ws_w,
                                                 float* __restrict__ out) {
    __shared__ float row[TS];

    int blk  = blockIdx.x;
    int p    = blk >> 2;         // SPLIT = 4
    int q    = blk & 3;
    int tid  = threadIdx.x;
    int lane = tid & 63;

    // per-wave reduce of 256 min/max partials (uint4 per lane, shuffle only)
    uint4 a = ((const uint4*)ws_min)[lane];
    uint4 c = ((const uint4*)ws_max)[lane];
    unsigned gmin = min(min(a.x, a.y), min(a.z, a.w));
    unsigned gmax = max(max(c.x, c.y), max(c.z, c.w));
    for (int off = 32; off > 0; off >>= 1) {
        gmin = min(gmin, (unsigned)__shfl_xor((int)gmin, off));
        gmax = max(gmax, (unsigned)__shfl_xor((int)gmax, off));
    }
    float minv  = fdec(gmin);
    float maxv  = fdec(gmax);
    float denom = (maxv - minv) + 0.001f;
    int   idx   = ws_idx[p];
    float scale = ws_w[p] / denom;
    float bias  = -minv * scale;

    // stage the normalized*w row in LDS (one barrier)
    {
        const f4* it4 = (const f4*)(items + (size_t)idx * TS);
        f4 r0 = it4[tid];
        f4 r1 = it4[tid + 256];
        row[tid * 4 + 0] = fmaf(r0.x, scale, bias);
        row[tid * 4 + 1] = fmaf(r0.y, scale, bias);
        row[tid * 4 + 2] = fmaf(r0.z, scale, bias);
        row[tid * 4 + 3] = fmaf(r0.w, scale, bias);
        row[(tid + 256) * 4 + 0] = fmaf(r1.x, scale, bias);
        row[(tid + 256) * 4 + 1] = fmaf(r1.y, scale, bias);
        row[(tid + 256) * 4 + 2] = fmaf(r1.z, scale, bias);
        row[(tid + 256) * 4 + 3] = fmaf(r1.w, scale, bias);
    }
    __syncthreads();

    constexpr int CHUNK = FULL / SPLIT;   // 8192 floats -> 2048 f4 per block
    const f4* nz4 = (const f4*)(noise + (size_t)p * FULL + (size_t)q * CHUNK);
    f4*       o4  = (f4*)(out + (size_t)p * PADDED + (size_t)q * CHUNK);
    int tbase = q * CHUNK;

    // prefetch all 8 noise vectors (8 outstanding loads/thread)
    f4 nzv[8];
    #pragma unroll
    for (int k = 0; k < 8; ++k)
        nzv[k] = nz4[tid + k * 256];

    #pragma unroll
    for (int k = 0; k < 8; ++k) {
        int v  = tid + k * 256;
        int t0 = tbase + v * 4;
        float pos0 = ((float)t0 + 0.5f) * 0.0625f - 0.5f;   // in/out = 1/16 exact
        f4 o;
        #pragma unroll
        for (int j = 0; j < 4; ++j) {
            float pj = fminf(fmaxf(pos0 + (float)j * 0.0625f, 0.0f), (float)(TS - 1));
            int   lj = (int)pj;                   // trunc == floor (>=0)
            int   hj = min(lj + 1, TS - 1);
            float fr = pj - (float)lj;
            float amp = row[lj] * (1.0f - fr) + row[hj] * fr;
            o[j] = amp * nzv[k][j];
        }
        __builtin_nontemporal_store(o, &o4[v]);
    }
}

extern "C" void kernel_launch(void* const* d_in, const int* in_sizes, int n_in,
                              void* d_out, int out_size, void* d_ws, size_t ws_size,
                              hipStream_t stream) {
    const float* sel   = (const float*)d_in[0];   // [8,64,512]
    const float* items = (const float*)d_in[1];   // [512,2048]
    const float* noise = (const float*)d_in[2];   // [8,64,32768]
    float* out = (float*)d_out;                   // [8,64,65536]

    unsigned* ws_min = (unsigned*)d_ws;
    unsigned* ws_max = (unsigned*)((char*)d_ws + 1024);
    int*      ws_idx = (int*)((char*)d_ws + 2048);
    float*    ws_w   = (float*)((char*)d_ws + 4096);

    hipLaunchKernelGGL(k_prep, dim3(NPAIR * 2), dim3(256), 0, stream,
                       (const f4*)items, sel, ws_min, ws_max, ws_idx, ws_w, out);
    hipLaunchKernelGGL(k_main, dim3(NPAIR * SPLIT), dim3(256), 0, stream,
                       items, noise, ws_min, ws_max, ws_idx, ws_w, out);
}